// Round 4
// baseline (168.778 us; speedup 1.0000x reference)
//
#include <hip/hip_runtime.h>

typedef unsigned short u16;
typedef unsigned int u32;
typedef __attribute__((ext_vector_type(8))) short short8;
typedef __attribute__((ext_vector_type(4))) short s16x4;
typedef __attribute__((ext_vector_type(4))) float f32x4;
typedef __attribute__((ext_vector_type(2))) u32 u32x2;

typedef const __attribute__((address_space(1))) void* gptr_t;
typedef __attribute__((address_space(3))) void* sptr_t;

#define N_SEQ 2048
#define DIM 1024
#define INNER 1024
#define NTOK 4096
#define QKV_LD 3072

__device__ __forceinline__ u16 f2b(float f) {
  union { float f; unsigned u; } v; v.f = f;
  unsigned r = v.u + 0x7fffu + ((v.u >> 16) & 1u);
  return (u16)(r >> 16);
}

// ---------------- cast x: fp32 -> bf16, 8 elems/thread ----------------
__global__ __launch_bounds__(256) void cast_x_kernel(const float* __restrict__ src,
                                                     u16* __restrict__ dst) {
  const size_t i = (size_t)blockIdx.x * 256 + threadIdx.x;
  const f32x4* s = (const f32x4*)(src + i * 8);
  f32x4 a = s[0], b = s[1];
  short8 o;
#pragma unroll
  for (int j = 0; j < 4; ++j) { o[j] = (short)f2b(a[j]); o[4 + j] = (short)f2b(b[j]); }
  *(short8*)(dst + i * 8) = o;
}

// ------------- transpose+cast W[1024][1024] f32 -> Wt[1024][1024] bf16 -------------
__global__ __launch_bounds__(256) void transpose_cast_kernel(const float* __restrict__ src,
                                                             u16* __restrict__ dst) {
  __shared__ u16 tile[64][65];
  const int n0 = blockIdx.x * 64, k0 = blockIdx.y * 64;
  for (int i = threadIdx.x; i < 4096; i += 256) {
    const int r = i >> 6, c = i & 63;
    tile[r][c] = f2b(src[(size_t)(k0 + r) * 1024 + n0 + c]);
  }
  __syncthreads();
  for (int i = threadIdx.x; i < 4096; i += 256) {
    const int r = i >> 6, c = i & 63;
    dst[(size_t)(n0 + r) * 1024 + k0 + c] = tile[c][r];
  }
}

// ------------- transpose V portion of qkv -> vt[bh][64][2048] bf16 -------------
__global__ __launch_bounds__(256) void transpose_v_kernel(const u16* __restrict__ qkv,
                                                          u16* __restrict__ vt) {
  __shared__ u16 t[64][72];
  const int nt0 = blockIdx.x * 64;
  const int bh = blockIdx.y;
  const int b = bh >> 4, h = bh & 15;
  const u16* src = qkv + (size_t)b * N_SEQ * QKV_LD + 2048 + h * 64;
#pragma unroll
  for (int i = 0; i < 2; ++i) {
    const int cid = i * 256 + threadIdx.x;
    const int r = cid >> 3, c = (cid & 7) * 8;
    *(short8*)&t[r][c] = *(const short8*)(src + (size_t)(nt0 + r) * QKV_LD + c);
  }
  __syncthreads();
#pragma unroll
  for (int i = 0; i < 2; ++i) {
    const int cid = i * 256 + threadIdx.x;
    const int d = cid >> 3, c = (cid & 7) * 8;
    short8 v;
#pragma unroll
    for (int j = 0; j < 8; ++j) v[j] = t[c + j][d];
    *(short8*)(vt + ((size_t)bh * 64 + d) * N_SEQ + nt0 + c) = v;
  }
}

// ---------------- TN GEMM: C[M][N] = A[M][K] * Bt[N][K]^T  (m97 + T1 XCD swizzle) ----------------
template <typename OutT>
__global__ __launch_bounds__(256) void gemm_tn(const u16* __restrict__ A,
                                               const u16* __restrict__ Bt,
                                               OutT* __restrict__ C,
                                               int M, int N, int K) {
  __shared__ u16 Al[128 * 64];
  __shared__ u16 Bl[128 * 64];
  const int tid = threadIdx.x;
  const int w = tid >> 6, lane = tid & 63;
  const int l15 = lane & 15, lg = lane >> 4;
  const int wr = w >> 1, wc = w & 1;
  // T1: bijective XCD swizzle (requires nwg % 8 == 0 — true for both launches)
  const int nwg = gridDim.x * gridDim.y;
  int bid = blockIdx.y * gridDim.x + blockIdx.x;
  bid = (bid & 7) * (nwg >> 3) + (bid >> 3);
  const int bx = bid % gridDim.x, by = bid / gridDim.x;
  const int m0 = by * 128, n0 = bx * 128;

  f32x4 acc[4][4] = {};

  for (int k0 = 0; k0 < K; k0 += 64) {
#pragma unroll
    for (int i = 0; i < 4; ++i) {
      const int chunk = (w << 2) + i;
      const int e = (chunk << 9) + lane * 8;
      const int row = e >> 6, col = e & 63;
      const u16* ga = A + (size_t)(m0 + row) * K + k0 + col;
      __builtin_amdgcn_global_load_lds((gptr_t)ga, (sptr_t)(Al + (chunk << 9)), 16, 0, 0);
      const u16* gb = Bt + (size_t)(n0 + row) * K + k0 + col;
      __builtin_amdgcn_global_load_lds((gptr_t)gb, (sptr_t)(Bl + (chunk << 9)), 16, 0, 0);
    }
    __syncthreads();
#pragma unroll
    for (int kk = 0; kk < 2; ++kk) {
      short8 af[4], bf[4];
#pragma unroll
      for (int m = 0; m < 4; ++m)
        af[m] = *(const short8*)(Al + ((wr * 64 + m * 16 + l15) << 6) + kk * 32 + lg * 8);
#pragma unroll
      for (int n = 0; n < 4; ++n)
        bf[n] = *(const short8*)(Bl + ((wc * 64 + n * 16 + l15) << 6) + kk * 32 + lg * 8);
#pragma unroll
      for (int m = 0; m < 4; ++m)
#pragma unroll
        for (int n = 0; n < 4; ++n)
          acc[m][n] = __builtin_amdgcn_mfma_f32_16x16x32_bf16(af[m], bf[n], acc[m][n], 0, 0, 0);
    }
    __syncthreads();
  }

#pragma unroll
  for (int m = 0; m < 4; ++m)
#pragma unroll
    for (int n = 0; n < 4; ++n)
#pragma unroll
      for (int r = 0; r < 4; ++r) {
        const int row = m0 + wr * 64 + m * 16 + lg * 4 + r;
        const int col = n0 + wc * 64 + n * 16 + l15;
        const float v = acc[m][n][r];
        if constexpr (sizeof(OutT) == 2) C[(size_t)row * N + col] = (OutT)f2b(v);
        else                             C[(size_t)row * N + col] = (OutT)v;
      }
}

// ---------------- causal flash attention (QBLK=128, KVBLK=128, 2 q-groups/wave) ----------------
// grid (32 bh, 16 qt-desc), 256 thr. Wave w owns q rows w*32..+32 as groups g=0,1 (row = l15).
__global__ __launch_bounds__(256) void attn_kernel(const u16* __restrict__ qkv,
                                                   const u16* __restrict__ vt,
                                                   u16* __restrict__ attnb) {
  const int bh = blockIdx.x;
  const int qt = 15 - (int)blockIdx.y;          // long blocks dispatch first
  const int b = bh >> 4, h = bh & 15;
  const int tid = threadIdx.x;
  const int lane = tid & 63, w = tid >> 6;
  const int l15 = lane & 15, lg = lane >> 4;
  const int q0 = qt * 128;
  const int qrow0 = q0 + w * 32 + l15;          // group-0 q row; group 1 = +16

  __shared__ u16 Kl[128 * 64];                  // K tile, 16B-chunk-swizzled
  __shared__ u16 Vl[64 * 128];                  // V^T tile, 16B-chunk-swizzled
  __shared__ u16 Pl[4][2][16][136];             // per-wave, per-group P relayout

  const u16* base  = qkv + (size_t)b * N_SEQ * QKV_LD;
  const u16* kbase = base + 1024 + h * 64;
  const u16* vbase = vt + (size_t)bh * 64 * N_SEQ;

  short8 aq[2][2];
#pragma unroll
  for (int g = 0; g < 2; ++g) {
    const u16* qp = base + (size_t)(qrow0 + g * 16) * QKV_LD + h * 64 + lg * 8;
    aq[g][0] = *(const short8*)qp;
    aq[g][1] = *(const short8*)(qp + 32);
  }

  f32x4 o[2][4] = {};
  float m_run[2] = {-3.0e38f, -3.0e38f}, l_run[2] = {0.f, 0.f};
  const float kscale = 0.125f * 1.4426950408889634f;   // scale * log2(e)
  const int nt = qt + 1;
  const int wbase = tid & ~63;                  // wave-uniform

  for (int jt = 0; jt < nt; ++jt) {
    const int kv0 = jt * 128;
    __syncthreads();                            // prior tile reads done
#pragma unroll
    for (int i = 0; i < 4; ++i) {
      const int cid = i * 256 + tid;
      const int krow = cid >> 3, kc = (cid & 7) ^ (krow & 7);
      const u16* ks = kbase + (size_t)(kv0 + krow) * QKV_LD + kc * 8;
      __builtin_amdgcn_global_load_lds((gptr_t)ks, (sptr_t)(Kl + (i * 256 + wbase) * 8), 16, 0, 0);
      const int vrow = cid >> 4, vc0 = cid & 15;
      const int vc = (vc0 & 8) | ((vc0 & 7) ^ (vrow & 7));
      const u16* vs = vbase + (size_t)vrow * N_SEQ + kv0 + vc * 8;
      __builtin_amdgcn_global_load_lds((gptr_t)vs, (sptr_t)(Vl + (i * 256 + wbase) * 8), 16, 0, 0);
    }
    __syncthreads();                            // vmcnt drained by barrier

    // S^T = K·Q^T: p[g][mf][r] = S[q=l15(+16g)][kv0 + mf*16 + lg*4 + r]
    f32x4 p[2][8];
#pragma unroll
    for (int mf = 0; mf < 8; ++mf) {
      short8 ak[2];
#pragma unroll
      for (int ks = 0; ks < 2; ++ks) {
        const int row = mf * 16 + l15;
        const int ch = (ks * 4 + lg) ^ (row & 7);
        ak[ks] = *(const short8*)(Kl + row * 64 + ch * 8);
      }
#pragma unroll
      for (int g = 0; g < 2; ++g) {
        f32x4 acc = {};
#pragma unroll
        for (int ks = 0; ks < 2; ++ks)
          acc = __builtin_amdgcn_mfma_f32_16x16x32_bf16(ak[ks], aq[g][ks], acc, 0, 0, 0);
        p[g][mf] = acc;
      }
    }

    if (jt == nt - 1) {                         // causal mask only on last tile
#pragma unroll
      for (int g = 0; g < 2; ++g)
#pragma unroll
        for (int mf = 0; mf < 8; ++mf)
#pragma unroll
          for (int r = 0; r < 4; ++r)
            if (kv0 + mf * 16 + lg * 4 + r > qrow0 + g * 16) p[g][mf][r] = -3.0e38f;
    }

#pragma unroll
    for (int g = 0; g < 2; ++g) {
      float mt = p[g][0][0];
#pragma unroll
      for (int mf = 0; mf < 8; ++mf)
#pragma unroll
        for (int r = 0; r < 4; ++r) mt = fmaxf(mt, p[g][mf][r]);
      mt = fmaxf(mt, __shfl_xor(mt, 16, 64));
      mt = fmaxf(mt, __shfl_xor(mt, 32, 64));
      const float mn = fmaxf(m_run[g], mt);
      const float sf = exp2f((m_run[g] - mn) * kscale);
      m_run[g] = mn;
      float psum = 0.f;
#pragma unroll
      for (int mf = 0; mf < 8; ++mf)
#pragma unroll
        for (int r = 0; r < 4; ++r) {
          const float e = exp2f((p[g][mf][r] - mn) * kscale);
          p[g][mf][r] = e;
          psum += e;
        }
      psum += __shfl_xor(psum, 16, 64);
      psum += __shfl_xor(psum, 32, 64);
      l_run[g] = l_run[g] * sf + psum;
#pragma unroll
      for (int mf = 0; mf < 4; ++mf) o[g][mf] *= sf;

      // P -> bf16 packed -> per-wave LDS (b64 writes)
#pragma unroll
      for (int mf = 0; mf < 8; ++mf) {
        u32 d0, d1;
        asm("v_cvt_pk_bf16_f32 %0, %1, %2" : "=v"(d0) : "v"(p[g][mf][0]), "v"(p[g][mf][1]));
        asm("v_cvt_pk_bf16_f32 %0, %1, %2" : "=v"(d1) : "v"(p[g][mf][2]), "v"(p[g][mf][3]));
        u32x2 dd = {d0, d1};
        *(u32x2*)&Pl[w][g][l15][mf * 16 + lg * 4] = dd;
      }
    }
    asm volatile("s_waitcnt lgkmcnt(0)" ::: "memory");

    short8 ap[2][4];
#pragma unroll
    for (int g = 0; g < 2; ++g)
#pragma unroll
      for (int ks = 0; ks < 4; ++ks)
        ap[g][ks] = *(const short8*)&Pl[w][g][l15][ks * 32 + lg * 8];

    // O^T += V^T · P^T : V fragment read once, used by both groups
#pragma unroll
    for (int mf = 0; mf < 4; ++mf)
#pragma unroll
      for (int ks = 0; ks < 4; ++ks) {
        const int row = mf * 16 + l15;
        const int ch = ks * 4 + lg;
        const int csw = (ch & 8) | ((ch & 7) ^ (row & 7));
        short8 av = *(const short8*)(Vl + row * 128 + csw * 8);
#pragma unroll
        for (int g = 0; g < 2; ++g)
          o[g][mf] = __builtin_amdgcn_mfma_f32_16x16x32_bf16(av, ap[g][ks], o[g][mf], 0, 0, 0);
      }
  }

#pragma unroll
  for (int g = 0; g < 2; ++g) {
    const float inv = 1.f / l_run[g];
#pragma unroll
    for (int mf = 0; mf < 4; ++mf) {
      s16x4 sv;
#pragma unroll
      for (int r = 0; r < 4; ++r) sv[r] = (short)f2b(o[g][mf][r] * inv);
      u16* op = attnb + ((size_t)b * N_SEQ + qrow0 + g * 16) * INNER + h * 64 + mf * 16 + lg * 4;
      *(s16x4*)op = sv;
    }
  }
}

extern "C" void kernel_launch(void* const* d_in, const int* in_sizes, int n_in,
                              void* d_out, int out_size, void* d_ws, size_t ws_size,
                              hipStream_t stream) {
  const float* x  = (const float*)d_in[0];
  const float* Wq = (const float*)d_in[1];
  const float* Wk = (const float*)d_in[2];
  const float* Wv = (const float*)d_in[3];
  const float* Wo = (const float*)d_in[4];
  float* out = (float*)d_out;

  u16* xb    = (u16*)d_ws;                               // [4096][1024]
  u16* wqkvt = xb    + (size_t)NTOK * DIM;               // [3072][1024]
  u16* wot   = wqkvt + (size_t)3 * INNER * DIM;          // [1024][1024]
  u16* qkv   = wot   + (size_t)DIM * INNER;              // [4096][3072]
  u16* attnb = qkv   + (size_t)NTOK * QKV_LD;            // [4096][1024]
  u16* vtb   = attnb + (size_t)NTOK * INNER;             // [32][64][2048]

  cast_x_kernel<<<dim3(NTOK * DIM / (256 * 8)), 256, 0, stream>>>(x, xb);
  transpose_cast_kernel<<<dim3(16, 16), 256, 0, stream>>>(Wq, wqkvt);
  transpose_cast_kernel<<<dim3(16, 16), 256, 0, stream>>>(Wk, wqkvt + (size_t)1024 * 1024);
  transpose_cast_kernel<<<dim3(16, 16), 256, 0, stream>>>(Wv, wqkvt + (size_t)2048 * 1024);
  transpose_cast_kernel<<<dim3(16, 16), 256, 0, stream>>>(Wo, wot);

  gemm_tn<u16><<<dim3(3072 / 128, 4096 / 128), 256, 0, stream>>>(xb, wqkvt, qkv, NTOK, 3072, DIM);
  transpose_v_kernel<<<dim3(32, 32), 256, 0, stream>>>(qkv, vtb);
  attn_kernel<<<dim3(32, 16), 256, 0, stream>>>(qkv, vtb, attnb);
  gemm_tn<float><<<dim3(1024 / 128, 4096 / 128), 256, 0, stream>>>(attnb, wot, out, NTOK, INNER, INNER);
}

// Round 6
// 158.802 us; speedup vs baseline: 1.0628x; 1.0628x over previous
//
#include <hip/hip_runtime.h>

typedef unsigned short u16;
typedef unsigned int u32;
typedef __attribute__((ext_vector_type(8))) short short8;
typedef __attribute__((ext_vector_type(4))) short s16x4;
typedef __attribute__((ext_vector_type(4))) float f32x4;
typedef __attribute__((ext_vector_type(16))) float f32x16;
typedef __attribute__((ext_vector_type(4))) u32 u32x4;

typedef const __attribute__((address_space(1))) void* gptr_t;
typedef __attribute__((address_space(3))) void* sptr_t;

#define N_SEQ 2048
#define DIM 1024
#define INNER 1024
#define NTOK 4096
#define QKV_LD 3072

__device__ __forceinline__ u16 f2b(float f) {
  union { float f; unsigned u; } v; v.f = f;
  unsigned r = v.u + 0x7fffu + ((v.u >> 16) & 1u);
  return (u16)(r >> 16);
}

// ---------------- cast x: fp32 -> bf16, 8 elems/thread ----------------
__global__ __launch_bounds__(256) void cast_x_kernel(const float* __restrict__ src,
                                                     u16* __restrict__ dst) {
  const size_t i = (size_t)blockIdx.x * 256 + threadIdx.x;
  const f32x4* s = (const f32x4*)(src + i * 8);
  f32x4 a = s[0], b = s[1];
  short8 o;
#pragma unroll
  for (int j = 0; j < 4; ++j) { o[j] = (short)f2b(a[j]); o[4 + j] = (short)f2b(b[j]); }
  *(short8*)(dst + i * 8) = o;
}

// ------------- transpose+cast W[1024][1024] f32 -> Wt[1024][1024] bf16 -------------
__global__ __launch_bounds__(256) void transpose_cast_kernel(const float* __restrict__ src,
                                                             u16* __restrict__ dst) {
  __shared__ u16 tile[64][65];
  const int n0 = blockIdx.x * 64, k0 = blockIdx.y * 64;
  for (int i = threadIdx.x; i < 4096; i += 256) {
    const int r = i >> 6, c = i & 63;
    tile[r][c] = f2b(src[(size_t)(k0 + r) * 1024 + n0 + c]);
  }
  __syncthreads();
  for (int i = threadIdx.x; i < 4096; i += 256) {
    const int r = i >> 6, c = i & 63;
    dst[(size_t)(n0 + r) * 1024 + k0 + c] = tile[c][r];
  }
}

// ------------- transpose V portion of qkv -> vt[bh][64][2048] bf16 -------------
__global__ __launch_bounds__(256) void transpose_v_kernel(const u16* __restrict__ qkv,
                                                          u16* __restrict__ vt) {
  __shared__ u16 t[64][72];
  const int nt0 = blockIdx.x * 64;
  const int bh = blockIdx.y;
  const int b = bh >> 4, h = bh & 15;
  const u16* src = qkv + (size_t)b * N_SEQ * QKV_LD + 2048 + h * 64;
#pragma unroll
  for (int i = 0; i < 2; ++i) {
    const int cid = i * 256 + threadIdx.x;
    const int r = cid >> 3, c = (cid & 7) * 8;
    *(short8*)&t[r][c] = *(const short8*)(src + (size_t)(nt0 + r) * QKV_LD + c);
  }
  __syncthreads();
#pragma unroll
  for (int i = 0; i < 2; ++i) {
    const int cid = i * 256 + threadIdx.x;
    const int d = cid >> 3, c = (cid & 7) * 8;
    short8 v;
#pragma unroll
    for (int j = 0; j < 8; ++j) v[j] = t[c + j][d];
    *(short8*)(vt + ((size_t)bh * 64 + d) * N_SEQ + nt0 + c) = v;
  }
}

// ---------------- TN GEMM: C[M][N] = A[M][K] * Bt[N][K]^T  (m97 + T1 XCD swizzle) ----------------
template <typename OutT>
__global__ __launch_bounds__(256) void gemm_tn(const u16* __restrict__ A,
                                               const u16* __restrict__ Bt,
                                               OutT* __restrict__ C,
                                               int M, int N, int K) {
  __shared__ u16 Al[128 * 64];
  __shared__ u16 Bl[128 * 64];
  const int tid = threadIdx.x;
  const int w = tid >> 6, lane = tid & 63;
  const int l15 = lane & 15, lg = lane >> 4;
  const int wr = w >> 1, wc = w & 1;
  const int nwg = gridDim.x * gridDim.y;
  int bid = blockIdx.y * gridDim.x + blockIdx.x;
  bid = (bid & 7) * (nwg >> 3) + (bid >> 3);
  const int bx = bid % gridDim.x, by = bid / gridDim.x;
  const int m0 = by * 128, n0 = bx * 128;

  f32x4 acc[4][4] = {};

  for (int k0 = 0; k0 < K; k0 += 64) {
#pragma unroll
    for (int i = 0; i < 4; ++i) {
      const int chunk = (w << 2) + i;
      const int e = (chunk << 9) + lane * 8;
      const int row = e >> 6, col = e & 63;
      const u16* ga = A + (size_t)(m0 + row) * K + k0 + col;
      __builtin_amdgcn_global_load_lds((gptr_t)ga, (sptr_t)(Al + (chunk << 9)), 16, 0, 0);
      const u16* gb = Bt + (size_t)(n0 + row) * K + k0 + col;
      __builtin_amdgcn_global_load_lds((gptr_t)gb, (sptr_t)(Bl + (chunk << 9)), 16, 0, 0);
    }
    __syncthreads();
#pragma unroll
    for (int kk = 0; kk < 2; ++kk) {
      short8 af[4], bf[4];
#pragma unroll
      for (int m = 0; m < 4; ++m)
        af[m] = *(const short8*)(Al + ((wr * 64 + m * 16 + l15) << 6) + kk * 32 + lg * 8);
#pragma unroll
      for (int n = 0; n < 4; ++n)
        bf[n] = *(const short8*)(Bl + ((wc * 64 + n * 16 + l15) << 6) + kk * 32 + lg * 8);
#pragma unroll
      for (int m = 0; m < 4; ++m)
#pragma unroll
        for (int n = 0; n < 4; ++n)
          acc[m][n] = __builtin_amdgcn_mfma_f32_16x16x32_bf16(af[m], bf[n], acc[m][n], 0, 0, 0);
    }
    __syncthreads();
  }

#pragma unroll
  for (int m = 0; m < 4; ++m)
#pragma unroll
    for (int n = 0; n < 4; ++n)
#pragma unroll
      for (int r = 0; r < 4; ++r) {
        const int row = m0 + wr * 64 + m * 16 + lg * 4 + r;
        const int col = n0 + wc * 64 + n * 16 + l15;
        const float v = acc[m][n][r];
        if constexpr (sizeof(OutT) == 2) C[(size_t)row * N + col] = (OutT)f2b(v);
        else                             C[(size_t)row * N + col] = (OutT)v;
      }
}

// ---------------- causal flash attention: 32x32 MFMA, P in registers ----------------
// grid (32 bh, 16 qt-desc), 256 thr. Wave w owns q rows w*32..+32 (q = lane&31).
__global__ __launch_bounds__(256) void attn_kernel(const u16* __restrict__ qkv,
                                                   const u16* __restrict__ vt,
                                                   u16* __restrict__ attnb) {
  const int bh = blockIdx.x;
  const int qt = 15 - (int)blockIdx.y;
  const int b = bh >> 4, h = bh & 15;
  const int tid = threadIdx.x;
  const int lane = tid & 63, w = tid >> 6;
  const int l31 = lane & 31, hh = lane >> 5;
  const int q0 = qt * 128;
  const int qrow = q0 + w * 32 + l31;

  __shared__ u16 Kl[128 * 64];                  // [kv][d], 3-bit chunk XOR swizzle
  __shared__ u16 Vl[64 * 128];                  // [d][kv], 4-bit chunk XOR swizzle

  const u16* base  = qkv + (size_t)b * N_SEQ * QKV_LD;
  const u16* kbase = base + 1024 + h * 64;
  const u16* vbase = vt + (size_t)bh * 64 * N_SEQ;

  // Q B-frags: bq[ks] = Q[qrow][ks*16 + hh*8 + j]
  short8 bq[4];
#pragma unroll
  for (int ks = 0; ks < 4; ++ks)
    bq[ks] = *(const short8*)(base + (size_t)qrow * QKV_LD + h * 64 + ks * 16 + hh * 8);

  f32x16 o0 = {}, o1 = {};                      // O^T d-tiles 0,1
  float m_run = -3.0e38f, l_run = 0.f;
  const float kscale = 0.125f * 1.4426950408889634f;
  const int nt = qt + 1;
  const int wbase = tid & ~63;

  for (int jt = 0; jt < nt; ++jt) {
    const int kv0 = jt * 128;
    __syncthreads();                            // prior tile reads done
#pragma unroll
    for (int i = 0; i < 4; ++i) {
      const int cid = i * 256 + tid;
      const int krow = cid >> 3, kc = (cid & 7) ^ (krow & 7);
      const u16* ks = kbase + (size_t)(kv0 + krow) * QKV_LD + kc * 8;
      __builtin_amdgcn_global_load_lds((gptr_t)ks, (sptr_t)(Kl + (i * 256 + wbase) * 8), 16, 0, 0);
      const int vrow = cid >> 4, vc = (cid & 15) ^ (vrow & 15);
      const u16* vs = vbase + (size_t)vrow * N_SEQ + kv0 + vc * 8;
      __builtin_amdgcn_global_load_lds((gptr_t)vs, (sptr_t)(Vl + (i * 256 + wbase) * 8), 16, 0, 0);
    }
    __syncthreads();                            // vmcnt drained by barrier

    const bool last = (jt == nt - 1);
#pragma unroll
    for (int sub = 0; sub < 2; ++sub) {
      if (last && sub == 1 && w < 2) continue;  // fully-masked subtile (wave-uniform)
      const int kv0s = kv0 + sub * 64;

      // S^T tiles: p0 = kv[kv0s..+31], p1 = kv[kv0s+32..+63]; col q = l31
      f32x16 p0 = {}, p1 = {};
#pragma unroll
      for (int ks = 0; ks < 4; ++ks) {
        const int r0 = sub * 64 + l31;
        const int r1 = r0 + 32;
        short8 ak0 = *(const short8*)(Kl + r0 * 64 + (((ks * 2 + hh) ^ (r0 & 7)) * 8));
        short8 ak1 = *(const short8*)(Kl + r1 * 64 + (((ks * 2 + hh) ^ (r1 & 7)) * 8));
        p0 = __builtin_amdgcn_mfma_f32_32x32x16_bf16(ak0, bq[ks], p0, 0, 0, 0);
        p1 = __builtin_amdgcn_mfma_f32_32x32x16_bf16(ak1, bq[ks], p1, 0, 0, 0);
      }

      if (last) {                               // causal mask: kv > qrow
        const int kvb = kv0s + 4 * hh;
#pragma unroll
        for (int r = 0; r < 16; ++r) {
          const int off = (r & 3) + 8 * (r >> 2);
          if (kvb + off > qrow)      p0[r] = -3.0e38f;
          if (kvb + 32 + off > qrow) p1[r] = -3.0e38f;
        }
      }

      // online softmax: lane-local over 32 regs + 1 shfl (paired lane = same q)
      float mt = -3.0e38f;
#pragma unroll
      for (int r = 0; r < 16; ++r) { mt = fmaxf(mt, p0[r]); mt = fmaxf(mt, p1[r]); }
      mt = fmaxf(mt, __shfl_xor(mt, 32, 64));
      const float mn = fmaxf(m_run, mt);
      const float sf = exp2f((m_run - mn) * kscale);
      m_run = mn;
      float ps = 0.f;
#pragma unroll
      for (int r = 0; r < 16; ++r) {
        const float e0 = exp2f((p0[r] - mn) * kscale);
        const float e1 = exp2f((p1[r] - mn) * kscale);
        p0[r] = e0; p1[r] = e1;
        ps += e0 + e1;
      }
      ps += __shfl_xor(ps, 32, 64);
      l_run = l_run * sf + ps;
      o0 *= sf; o1 *= sf;

      // P -> bf16 PV B-frags via cvt_pk + permlane32_swap (no LDS).
      // v_permlane32_swap_b32 vdst, vsrc: vdst.hi <-> vsrc.lo (derived from HK T12 recipe).
      // swap(X, Y): X' = {X.lo, Y.lo} (word c2), Y' = {X.hi, Y.hi} (word 2+c2).
      u32 bpw[4][4];
#define PACK_TILE(P, kf)                                                    \
      {                                                                     \
        _Pragma("unroll")                                                   \
        for (int a2 = 0; a2 < 2; ++a2) {                                    \
          _Pragma("unroll")                                                 \
          for (int c2 = 0; c2 < 2; ++c2) {                                  \
            u32 X, Y;                                                       \
            asm("v_cvt_pk_bf16_f32 %0, %1, %2" : "=v"(X)                    \
                : "v"(P[8 * a2 + 2 * c2]), "v"(P[8 * a2 + 2 * c2 + 1]));    \
            asm("v_cvt_pk_bf16_f32 %0, %1, %2" : "=v"(Y)                    \
                : "v"(P[8 * a2 + 4 + 2 * c2]), "v"(P[8 * a2 + 5 + 2 * c2]));\
            asm("v_permlane32_swap_b32 %0, %1" : "+v"(X), "+v"(Y));         \
            bpw[(kf) * 2 + a2][c2] = X;      /* {X.lo, Y.lo} */             \
            bpw[(kf) * 2 + a2][2 + c2] = Y;  /* {X.hi, Y.hi} */             \
          }                                                                 \
        }                                                                   \
      }
      PACK_TILE(p0, 0)
      PACK_TILE(p1, 1)
#undef PACK_TILE

      // O^T += V^T · P^T
#pragma unroll
      for (int ks16 = 0; ks16 < 4; ++ks16) {
        u32x4 t = {bpw[ks16][0], bpw[ks16][1], bpw[ks16][2], bpw[ks16][3]};
        short8 bp = __builtin_bit_cast(short8, t);
        const int cb = sub * 8 + ks16 * 2 + hh;
        const int row0 = l31;
        const int row1 = 32 + l31;
        short8 av0 = *(const short8*)(Vl + row0 * 128 + ((cb ^ (row0 & 15)) * 8));
        short8 av1 = *(const short8*)(Vl + row1 * 128 + ((cb ^ (row1 & 15)) * 8));
        o0 = __builtin_amdgcn_mfma_f32_32x32x16_bf16(av0, bp, o0, 0, 0, 0);
        o1 = __builtin_amdgcn_mfma_f32_32x32x16_bf16(av1, bp, o1, 0, 0, 0);
      }
    }
  }

  const float inv = 1.f / l_run;
  u16* orow = attnb + ((size_t)b * N_SEQ + qrow) * INNER + h * 64 + 4 * hh;
#pragma unroll
  for (int rq = 0; rq < 4; ++rq) {
    s16x4 sv0, sv1;
#pragma unroll
    for (int j = 0; j < 4; ++j) {
      sv0[j] = (short)f2b(o0[rq * 4 + j] * inv);
      sv1[j] = (short)f2b(o1[rq * 4 + j] * inv);
    }
    *(s16x4*)(orow + rq * 8) = sv0;
    *(s16x4*)(orow + 32 + rq * 8) = sv1;
  }
}

extern "C" void kernel_launch(void* const* d_in, const int* in_sizes, int n_in,
                              void* d_out, int out_size, void* d_ws, size_t ws_size,
                              hipStream_t stream) {
  const float* x  = (const float*)d_in[0];
  const float* Wq = (const float*)d_in[1];
  const float* Wk = (const float*)d_in[2];
  const float* Wv = (const float*)d_in[3];
  const float* Wo = (const float*)d_in[4];
  float* out = (float*)d_out;

  u16* xb    = (u16*)d_ws;                               // [4096][1024]
  u16* wqkvt = xb    + (size_t)NTOK * DIM;               // [3072][1024]
  u16* wot   = wqkvt + (size_t)3 * INNER * DIM;          // [1024][1024]
  u16* qkv   = wot   + (size_t)DIM * INNER;              // [4096][3072]
  u16* attnb = qkv   + (size_t)NTOK * QKV_LD;            // [4096][1024]
  u16* vtb   = attnb + (size_t)NTOK * INNER;             // [32][64][2048]

  cast_x_kernel<<<dim3(NTOK * DIM / (256 * 8)), 256, 0, stream>>>(x, xb);
  transpose_cast_kernel<<<dim3(16, 16), 256, 0, stream>>>(Wq, wqkvt);
  transpose_cast_kernel<<<dim3(16, 16), 256, 0, stream>>>(Wk, wqkvt + (size_t)1024 * 1024);
  transpose_cast_kernel<<<dim3(16, 16), 256, 0, stream>>>(Wv, wqkvt + (size_t)2048 * 1024);
  transpose_cast_kernel<<<dim3(16, 16), 256, 0, stream>>>(Wo, wot);

  gemm_tn<u16><<<dim3(3072 / 128, 4096 / 128), 256, 0, stream>>>(xb, wqkvt, qkv, NTOK, 3072, DIM);
  transpose_v_kernel<<<dim3(32, 32), 256, 0, stream>>>(qkv, vtb);
  attn_kernel<<<dim3(32, 16), 256, 0, stream>>>(qkv, vtb, attnb);
  gemm_tn<float><<<dim3(1024 / 128, 4096 / 128), 256, 0, stream>>>(attnb, wot, out, NTOK, INNER, INNER);
}